// Round 4
// baseline (9107.245 us; speedup 1.0000x reference)
//
#include <hip/hip_runtime.h>

#define NN 262144
#define HH 128
#define EE 16
#define MAXD 12
#define CAP 8192          // per-(depth,category) capacity; expected ~5041
#define GBLK 512          // 2 blocks/CU: guaranteed co-resident via __launch_bounds__(256,2)
#define NTHR 256
#define G_LEP 384         // phase-2 split: [0,G_LEP) lep MLP, rest scatter
#define G_MRG 256         // phase-3 split: [0,G_MRG) merger, rest lem

struct CoopParams {
    const float* x_in;
    const int*   parents;
    const int*   depths;
    const int*   states;
    const float* pef;
    const float* plef;
    const float *mW1, *mb1, *mW2, *mb2;
    const float *pW1, *pb1, *pW2, *pb2;
    const float *eW1, *eb1, *eW2, *eb2;
    float* x;
    int *cntB, *cntA;          // cntB[36] bucket counts; cntA[24] active L/H counts
    int *bar;                  // grid barrier counter (zeroed per launch)
    int *flagL, *flagH, *slotL, *slotH;
    int *listL, *listR, *listHd, *activeL, *activeH;
    float *left_c, *right_c, *mh_c;
};

// ---------------------------------------------------------------------------
// software grid barrier: monotonic counter, release-add + acquire-spin.
// Safe because all GBLK blocks are co-resident (see __launch_bounds__ note).
__device__ __forceinline__ void gbar(int* bar, int target) {
    __syncthreads();
    if (threadIdx.x == 0) {
        __hip_atomic_fetch_add(bar, 1, __ATOMIC_RELEASE, __HIP_MEMORY_SCOPE_AGENT);
        while (__hip_atomic_load(bar, __ATOMIC_ACQUIRE, __HIP_MEMORY_SCOPE_AGENT) < target)
            __builtin_amdgcn_s_sleep(2);
    }
    __syncthreads();
}

// ---------------------------------------------------------------------------
// 2-layer MLP over 8 rows, 256 threads, split-K across 2 half-groups (h=tid>>7).
// MODE 0 (merger): rows=activeL; in=[left_c,right_c,pef[p]]; x[p] = out
// MODE 1 (lep):    rows=listHd;  in=[x[c],plef[c]]; atomicAdd mh_c[slotH[parent]]
// MODE 2 (lem):    rows=activeH; in=[x[p],mh_c]; x[p] = out if flagL[p]!=depth
template <int MODE, int INDIM>
__device__ __forceinline__
void mlp_core(int rowBase, int n, int tid,
              const int* __restrict__ rowList,
              const int* __restrict__ parents, const int* __restrict__ slotH,
              const int* __restrict__ flagL, int depth,
              const float* __restrict__ src0, const float* __restrict__ src1,
              const float* __restrict__ src2,
              const float* __restrict__ W1, const float* __restrict__ b1,
              const float* __restrict__ W2, const float* __restrict__ b2,
              float* __restrict__ out, float* sh_raw) {
    float (*sh_in)[INDIM] = (float (*)[INDIM])sh_raw;
    float (*sh_h)[HH]     = (float (*)[HH])(sh_raw + 8 * INDIM);
    float (*sh_pt)[HH]    = (float (*)[HH])(sh_raw + 8 * INDIM + 8 * HH);

    __syncthreads();   // protect shared reuse across loop iterations / phases

    for (int idx = tid; idx < 8 * INDIM; idx += 256) {
        int r = idx / INDIM, k = idx - r * INDIM;
        int g = rowBase + r;
        float v = 0.f;
        if (g < n) {
            if (MODE == 0) {
                v = (k < HH)     ? src0[(size_t)g * HH + k]
                  : (k < 2 * HH) ? src1[(size_t)g * HH + (k - HH)]
                                 : src2[(size_t)rowList[g] * EE + (k - 2 * HH)];
            } else if (MODE == 1) {
                int c = rowList[g];
                v = (k < HH) ? src0[(size_t)c * HH + k]
                             : src1[(size_t)c * EE + (k - HH)];
            } else {
                v = (k < HH) ? src0[(size_t)rowList[g] * HH + k]
                             : src1[(size_t)g * HH + (k - HH)];
            }
        }
        sh_in[r][k] = v;
    }
    __syncthreads();

    const int h = tid >> 7, j = tid & 127;
    constexpr int KH1 = INDIM / 2;
    float acc[8];
    #pragma unroll
    for (int r = 0; r < 8; ++r) acc[r] = 0.f;
    {
        const float* Wp = W1 + (size_t)h * KH1 * HH + j;
        for (int k = 0; k < KH1; k += 8) {
            float wv[8];
            #pragma unroll
            for (int u = 0; u < 8; ++u) wv[u] = Wp[(size_t)(k + u) * HH];
            #pragma unroll
            for (int u = 0; u < 8; ++u) {
                float w = wv[u];
                int kk = h * KH1 + k + u;
                #pragma unroll
                for (int r = 0; r < 8; ++r) acc[r] += sh_in[r][kk] * w;
            }
        }
    }
    if (h == 1) {
        #pragma unroll
        for (int r = 0; r < 8; ++r) sh_pt[r][j] = acc[r];
    }
    __syncthreads();
    if (h == 0) {
        float bb = b1[j];
        #pragma unroll
        for (int r = 0; r < 8; ++r) sh_h[r][j] = fmaxf(acc[r] + sh_pt[r][j] + bb, 0.f);
    }
    __syncthreads();

    float acc2[8];
    #pragma unroll
    for (int r = 0; r < 8; ++r) acc2[r] = 0.f;
    {
        const float* Wp = W2 + (size_t)h * (HH / 2) * HH + j;
        for (int k = 0; k < HH / 2; k += 8) {
            float wv[8];
            #pragma unroll
            for (int u = 0; u < 8; ++u) wv[u] = Wp[(size_t)(k + u) * HH];
            #pragma unroll
            for (int u = 0; u < 8; ++u) {
                float w = wv[u];
                int kk = h * (HH / 2) + k + u;
                #pragma unroll
                for (int r = 0; r < 8; ++r) acc2[r] += sh_h[r][kk] * w;
            }
        }
    }
    if (h == 1) {
        #pragma unroll
        for (int r = 0; r < 8; ++r) sh_pt[r][j] = acc2[r];
    }
    __syncthreads();
    if (h == 0) {
        float bb2 = b2[j];
        for (int r = 0; r < 8; ++r) {
            int g = rowBase + r;
            if (g >= n) break;
            float val = acc2[r] + sh_pt[r][j] + bb2;
            if (MODE == 1) {
                atomicAdd(&out[(size_t)slotH[parents[rowList[g]]] * HH + j], val);
            } else if (MODE == 0) {
                out[(size_t)rowList[g] * HH + j] = val;
            } else {
                int p = rowList[g];
                if (flagL[p] != depth)
                    out[(size_t)p * HH + j] = val;
            }
        }
    }
}

// ---------------------------------------------------------------------------
// __launch_bounds__(256, 2): min 2 waves/EU -> VGPR capped at 256 -> at least
// 2 blocks/CU schedulable (LDS 17.2KB is not the limit). grid=512 = 2*256CU,
// so ALL blocks are co-resident and the software barrier cannot deadlock.
__global__ __launch_bounds__(NTHR, 2)
void persist_kernel(CoopParams prm) {
    const int bid = blockIdx.x, tid = threadIdx.x;
    const int gtid = bid * NTHR + tid;
    const int gsize = GBLK * NTHR;
    int barT = 0;

    __shared__ float sh_raw[8 * (2 * HH + EE) + 16 * HH];
    __shared__ int lcnt[36], lbase[36];
    __shared__ int lc[2], lb[2];

    // ---------------- phase 0: flags, x copy, bucket ----------------------
    for (int i = gtid; i < NN; i += gsize) { prm.flagL[i] = -1; prm.flagH[i] = -1; }

    {   // x copy (float4)
        const float4* src = (const float4*)prm.x_in;
        float4* dst = (float4*)prm.x;
        for (int i = gtid; i < NN * HH / 4; i += gsize) dst[i] = src[i];
    }
    {   // bucket: each block owns a contiguous chunk of NN/GBLK = 512 nodes
        if (tid < 36) lcnt[tid] = 0;
        __syncthreads();
        int base = bid * (NN / GBLK);
        int bkt[2], rnk[2];
        #pragma unroll
        for (int u = 0; u < 2; ++u) {
            int i = base + u * NTHR + tid;
            int d = prm.depths[i], s = prm.states[i];
            bkt[u] = -1; rnk[u] = 0;
            if (d >= 1 && (s == 0 || s == 1 || s == 3)) {
                int cat = (s == 3) ? 2 : s;
                bkt[u] = (d - 1) * 3 + cat;
                rnk[u] = atomicAdd(&lcnt[bkt[u]], 1);
            }
        }
        __syncthreads();
        if (tid < 36 && lcnt[tid] > 0) lbase[tid] = atomicAdd(&prm.cntB[tid], lcnt[tid]);
        __syncthreads();
        #pragma unroll
        for (int u = 0; u < 2; ++u) {
            if (bkt[u] >= 0) {
                int idx = lbase[bkt[u]] + rnk[u];
                if (idx < CAP) {
                    int dd = bkt[u] / 3, cat = bkt[u] - dd * 3;
                    int i = base + u * NTHR + tid;
                    int* lst = (cat == 0) ? prm.listL : (cat == 1) ? prm.listR : prm.listHd;
                    lst[dd * CAP + idx] = i;
                }
            }
        }
    }
    gbar(prm.bar, barT += GBLK);

    // ---------------- depth loop ------------------------------------------
    for (int d = MAXD; d >= 1; --d) {
        const int bi = d - 1;
        const int* listL  = prm.listL  + (size_t)bi * CAP;
        const int* listR  = prm.listR  + (size_t)bi * CAP;
        const int* listHd = prm.listHd + (size_t)bi * CAP;

        // ---- phase 1: mark parents, alloc slots, zero compact rows -------
        {
            int nL = min(prm.cntB[bi * 3 + 0], CAP);
            int nH = min(prm.cntB[bi * 3 + 2], CAP);
            if (tid < 2) lc[tid] = 0;
            __syncthreads();
            int t = gtid;   // gsize = 131072 >= nL+nH (<= 16384) always
            int p = -1, which = 0, rank = 0;
            if (t < nL + nH) {
                which = (t >= nL) ? 1 : 0;
                p = which ? prm.parents[listHd[t - nL]] : prm.parents[listL[t]];
                int* flag = which ? prm.flagH : prm.flagL;
                int old = atomicExch(&flag[p], d);
                if (old != d) rank = atomicAdd(&lc[which], 1);
                else p = -1;
            }
            __syncthreads();
            if (tid < 2 && lc[tid] > 0)
                lb[tid] = atomicAdd(&prm.cntA[(tid ? 12 : 0) + bi], lc[tid]);
            __syncthreads();
            if (p >= 0) {
                int s = lb[which] + rank;
                float4 z = make_float4(0.f, 0.f, 0.f, 0.f);
                if (which) {
                    prm.slotH[p] = s; prm.activeH[s] = p;
                    float4* a = (float4*)(prm.mh_c + (size_t)s * HH);
                    #pragma unroll
                    for (int q = 0; q < HH / 4; ++q) a[q] = z;
                } else {
                    prm.slotL[p] = s; prm.activeL[s] = p;
                    float4* a  = (float4*)(prm.left_c  + (size_t)s * HH);
                    float4* b2 = (float4*)(prm.right_c + (size_t)s * HH);
                    #pragma unroll
                    for (int q = 0; q < HH / 4; ++q) { a[q] = z; b2[q] = z; }
                }
            }
        }
        gbar(prm.bar, barT += GBLK);

        // ---- phase 2: lep MLP [0,G_LEP) || left/right scatter [G_LEP,GBLK)
        if (bid < G_LEP) {
            int nH = min(prm.cntB[bi * 3 + 2], CAP);
            for (int rb = bid; rb * 8 < nH; rb += G_LEP)
                mlp_core<1, HH + EE>(rb * 8, nH, tid, listHd, prm.parents, prm.slotH,
                                     prm.flagL, d, prm.x, prm.plef, nullptr,
                                     prm.pW1, prm.pb1, prm.pW2, prm.pb2,
                                     prm.mh_c, sh_raw);
        } else {
            int nL = min(prm.cntB[bi * 3 + 0], CAP);
            int nR = min(prm.cntB[bi * 3 + 1], CAP);
            int total = (nL + nR) * (HH / 4);
            for (int t = (bid - G_LEP) * NTHR + tid; t < total;
                 t += (GBLK - G_LEP) * NTHR) {
                int e = t >> 5, q = t & 31;
                int child;
                float* dst;
                if (e < nL) {
                    child = listL[e];
                    dst = prm.left_c + (size_t)prm.slotL[prm.parents[child]] * HH;
                } else {
                    child = listR[e - nL];
                    int p = prm.parents[child];
                    if (prm.flagL[p] != d) continue;   // no left sibling: never applied
                    dst = prm.right_c + (size_t)prm.slotL[p] * HH;
                }
                float4 v = ((const float4*)(prm.x + (size_t)child * HH))[q];
                atomicAdd(dst + q * 4 + 0, v.x);
                atomicAdd(dst + q * 4 + 1, v.y);
                atomicAdd(dst + q * 4 + 2, v.z);
                atomicAdd(dst + q * 4 + 3, v.w);
            }
        }
        gbar(prm.bar, barT += GBLK);

        // ---- phase 3: merger [0,G_MRG) || lem [G_MRG,GBLK) ---------------
        // merger writes x[p] for left-parents; lem reads x[p] for head-parents.
        // Overlap rows are exactly those where lem output is discarded (flagL
        // priority), so the read-write overlap there is harmless.
        if (bid < G_MRG) {
            int nA = min(prm.cntA[bi], CAP);
            for (int rb = bid; rb * 8 < nA; rb += G_MRG)
                mlp_core<0, 2 * HH + EE>(rb * 8, nA, tid, prm.activeL, prm.parents,
                                         nullptr, prm.flagL, d,
                                         prm.left_c, prm.right_c, prm.pef,
                                         prm.mW1, prm.mb1, prm.mW2, prm.mb2,
                                         prm.x, sh_raw);
        } else {
            int nB = min(prm.cntA[12 + bi], CAP);
            for (int rb = bid - G_MRG; rb * 8 < nB; rb += GBLK - G_MRG)
                mlp_core<2, 2 * HH>(rb * 8, nB, tid, prm.activeH, prm.parents,
                                    nullptr, prm.flagL, d,
                                    prm.x, prm.mh_c, nullptr,
                                    prm.eW1, prm.eb1, prm.eW2, prm.eb2,
                                    prm.x, sh_raw);
        }
        gbar(prm.bar, barT += GBLK);
    }
}

// ---------------------------------------------------------------------------
extern "C" void kernel_launch(void* const* d_in, const int* in_sizes, int n_in,
                              void* d_out, int out_size, void* d_ws, size_t ws_size,
                              hipStream_t stream) {
    CoopParams prm;
    prm.x_in    = (const float*)d_in[0];
    const int* edge = (const int*)d_in[1];
    prm.depths  = (const int*)d_in[2];
    prm.states  = (const int*)d_in[3];
    prm.pef     = (const float*)d_in[4];
    prm.plef    = (const float*)d_in[5];
    prm.mW1 = (const float*)d_in[6];  prm.mb1 = (const float*)d_in[7];
    prm.mW2 = (const float*)d_in[8];  prm.mb2 = (const float*)d_in[9];
    prm.pW1 = (const float*)d_in[10]; prm.pb1 = (const float*)d_in[11];
    prm.pW2 = (const float*)d_in[12]; prm.pb2 = (const float*)d_in[13];
    prm.eW1 = (const float*)d_in[14]; prm.eb1 = (const float*)d_in[15];
    prm.eW2 = (const float*)d_in[16]; prm.eb2 = (const float*)d_in[17];

    prm.x = (float*)d_out;
    prm.parents = edge + NN;

    char* w = (char*)d_ws;
    auto alloc = [&](size_t bytes) {
        void* p = (void*)w;
        w += (bytes + 255) & ~(size_t)255;
        return p;
    };
    int* cnt_all = (int*)alloc(64 * 4);     // [0..35]=cntB, [36..59]=cntA, [60]=bar
    prm.cntB   = cnt_all;
    prm.cntA   = cnt_all + 36;
    prm.bar    = cnt_all + 60;
    prm.flagL  = (int*)alloc((size_t)NN * 4);
    prm.flagH  = (int*)alloc((size_t)NN * 4);
    prm.slotL  = (int*)alloc((size_t)NN * 4);
    prm.slotH  = (int*)alloc((size_t)NN * 4);
    prm.listL  = (int*)alloc((size_t)12 * CAP * 4);
    prm.listR  = (int*)alloc((size_t)12 * CAP * 4);
    prm.listHd = (int*)alloc((size_t)12 * CAP * 4);
    prm.activeL = (int*)alloc((size_t)CAP * 4);
    prm.activeH = (int*)alloc((size_t)CAP * 4);
    prm.left_c  = (float*)alloc((size_t)CAP * HH * 4);
    prm.right_c = (float*)alloc((size_t)CAP * HH * 4);
    prm.mh_c    = (float*)alloc((size_t)CAP * HH * 4);

    hipMemsetAsync(cnt_all, 0, 64 * 4, stream);   // zeroes cntB, cntA, bar

    persist_kernel<<<dim3(GBLK), dim3(NTHR), 0, stream>>>(prm);
}

// Round 5
// 2321.274 us; speedup vs baseline: 3.9234x; 3.9234x over previous
//
#include <hip/hip_runtime.h>

#define NN 262144
#define HH 128
#define EE 16
#define MAXD 12
#define CAP 8192          // per-(depth,category) capacity; expected ~5041
#define GBLK 512          // 2 blocks/CU: co-resident via __launch_bounds__(256,2) (proved in R4)
#define NTHR 256
#define G_LEP 384         // phase-2 split: [0,G_LEP) lep MLP, rest scatter
#define G_MRG 256         // phase-3 split: [0,G_MRG) merger, rest lem
#define NGRP 8            // barrier groups (separate cachelines)
#define GPG (GBLK / NGRP) // 64 blocks per group

struct CoopParams {
    const float* x_in;
    const int*   parents;
    const int*   depths;
    const int*   states;
    const float* pef;
    const float* plef;
    const float *mW1, *mb1, *mW2, *mb2;
    const float *pW1, *pb1, *pW2, *pb2;
    const float *eW1, *eb1, *eW2, *eb2;
    float* x;
    int *cntB, *cntA;          // cntB[36] bucket counts; cntA[24] active L/H counts
    int *bars;                 // barrier: group g at bars[g*32], master at bars[NGRP*32]
    int *flagL, *flagH, *slotL, *slotH;
    int *listL, *listR, *listHd, *activeL, *activeH;
    float *left_c, *right_c, *mh_c;
};

// ---------------------------------------------------------------------------
// software grid barrier, hierarchical, relaxed-spin + single fences.
// Per-poll loads are RELAXED (no cache invalidation); exactly one
// fence(acquire) per block per barrier after it opens, one fence(release)
// before arrival. Avoids R4's per-poll L2-invalidation storm.
__device__ __forceinline__ void gbar(int* bars, int round) {
    __syncthreads();
    if (threadIdx.x == 0) {
        int g = blockIdx.x / GPG;
        __builtin_amdgcn_fence(__ATOMIC_RELEASE, "agent");
        int old = __hip_atomic_fetch_add(&bars[g * 32], 1, __ATOMIC_RELAXED,
                                         __HIP_MEMORY_SCOPE_AGENT);
        if (old + 1 == round * GPG) {            // last arriver of this group
            __builtin_amdgcn_fence(__ATOMIC_ACQUIRE, "agent");
            __builtin_amdgcn_fence(__ATOMIC_RELEASE, "agent");
            __hip_atomic_fetch_add(&bars[NGRP * 32], 1, __ATOMIC_RELAXED,
                                   __HIP_MEMORY_SCOPE_AGENT);
        }
        while (__hip_atomic_load(&bars[NGRP * 32], __ATOMIC_RELAXED,
                                 __HIP_MEMORY_SCOPE_AGENT) < round * NGRP)
            __builtin_amdgcn_s_sleep(4);
        __builtin_amdgcn_fence(__ATOMIC_ACQUIRE, "agent");
    }
    __syncthreads();
}

// ---------------------------------------------------------------------------
// 2-layer MLP over 8 rows, 256 threads, split-K across 2 half-groups (h=tid>>7).
// MODE 0 (merger): rows=activeL; in=[left_c,right_c,pef[p]]; x[p] = out
// MODE 1 (lep):    rows=listHd;  in=[x[c],plef[c]]; atomicAdd mh_c[slotH[parent]]
// MODE 2 (lem):    rows=activeH; in=[x[p],mh_c]; x[p] = out if flagL[p]!=depth
template <int MODE, int INDIM>
__device__ __forceinline__
void mlp_core(int rowBase, int n, int tid,
              const int* __restrict__ rowList,
              const int* __restrict__ parents, const int* __restrict__ slotH,
              const int* __restrict__ flagL, int depth,
              const float* __restrict__ src0, const float* __restrict__ src1,
              const float* __restrict__ src2,
              const float* __restrict__ W1, const float* __restrict__ b1,
              const float* __restrict__ W2, const float* __restrict__ b2,
              float* __restrict__ out, float* sh_raw) {
    float (*sh_in)[INDIM] = (float (*)[INDIM])sh_raw;
    float (*sh_h)[HH]     = (float (*)[HH])(sh_raw + 8 * INDIM);
    float (*sh_pt)[HH]    = (float (*)[HH])(sh_raw + 8 * INDIM + 8 * HH);

    __syncthreads();   // protect shared reuse across loop iterations / phases

    for (int idx = tid; idx < 8 * INDIM; idx += 256) {
        int r = idx / INDIM, k = idx - r * INDIM;
        int g = rowBase + r;
        float v = 0.f;
        if (g < n) {
            if (MODE == 0) {
                v = (k < HH)     ? src0[(size_t)g * HH + k]
                  : (k < 2 * HH) ? src1[(size_t)g * HH + (k - HH)]
                                 : src2[(size_t)rowList[g] * EE + (k - 2 * HH)];
            } else if (MODE == 1) {
                int c = rowList[g];
                v = (k < HH) ? src0[(size_t)c * HH + k]
                             : src1[(size_t)c * EE + (k - HH)];
            } else {
                v = (k < HH) ? src0[(size_t)rowList[g] * HH + k]
                             : src1[(size_t)g * HH + (k - HH)];
            }
        }
        sh_in[r][k] = v;
    }
    __syncthreads();

    const int h = tid >> 7, j = tid & 127;
    constexpr int KH1 = INDIM / 2;
    float acc[8];
    #pragma unroll
    for (int r = 0; r < 8; ++r) acc[r] = 0.f;
    {
        const float* Wp = W1 + (size_t)h * KH1 * HH + j;
        for (int k = 0; k < KH1; k += 8) {
            float wv[8];
            #pragma unroll
            for (int u = 0; u < 8; ++u) wv[u] = Wp[(size_t)(k + u) * HH];
            #pragma unroll
            for (int u = 0; u < 8; ++u) {
                float w = wv[u];
                int kk = h * KH1 + k + u;
                #pragma unroll
                for (int r = 0; r < 8; ++r) acc[r] += sh_in[r][kk] * w;
            }
        }
    }
    if (h == 1) {
        #pragma unroll
        for (int r = 0; r < 8; ++r) sh_pt[r][j] = acc[r];
    }
    __syncthreads();
    if (h == 0) {
        float bb = b1[j];
        #pragma unroll
        for (int r = 0; r < 8; ++r) sh_h[r][j] = fmaxf(acc[r] + sh_pt[r][j] + bb, 0.f);
    }
    __syncthreads();

    float acc2[8];
    #pragma unroll
    for (int r = 0; r < 8; ++r) acc2[r] = 0.f;
    {
        const float* Wp = W2 + (size_t)h * (HH / 2) * HH + j;
        for (int k = 0; k < HH / 2; k += 8) {
            float wv[8];
            #pragma unroll
            for (int u = 0; u < 8; ++u) wv[u] = Wp[(size_t)(k + u) * HH];
            #pragma unroll
            for (int u = 0; u < 8; ++u) {
                float w = wv[u];
                int kk = h * (HH / 2) + k + u;
                #pragma unroll
                for (int r = 0; r < 8; ++r) acc2[r] += sh_h[r][kk] * w;
            }
        }
    }
    if (h == 1) {
        #pragma unroll
        for (int r = 0; r < 8; ++r) sh_pt[r][j] = acc2[r];
    }
    __syncthreads();
    if (h == 0) {
        float bb2 = b2[j];
        for (int r = 0; r < 8; ++r) {
            int g = rowBase + r;
            if (g >= n) break;
            float val = acc2[r] + sh_pt[r][j] + bb2;
            if (MODE == 1) {
                atomicAdd(&out[(size_t)slotH[parents[rowList[g]]] * HH + j], val);
            } else if (MODE == 0) {
                out[(size_t)rowList[g] * HH + j] = val;
            } else {
                int p = rowList[g];
                if (flagL[p] != depth)
                    out[(size_t)p * HH + j] = val;
            }
        }
    }
}

// ---------------------------------------------------------------------------
// __launch_bounds__(256, 2): VGPR capped so >=2 blocks/CU schedulable; grid
// 512 = 2*256CU -> all blocks co-resident (R4 proved no deadlock).
__global__ __launch_bounds__(NTHR, 2)
void persist_kernel(CoopParams prm) {
    const int bid = blockIdx.x, tid = threadIdx.x;
    const int gtid = bid * NTHR + tid;
    const int gsize = GBLK * NTHR;
    int rnd = 0;

    __shared__ float sh_raw[8 * (2 * HH + EE) + 16 * HH];
    __shared__ int lcnt[36], lbase[36];
    __shared__ int lc[2], lb[2];

    // ---------------- phase 0: flags, x copy, bucket ----------------------
    for (int i = gtid; i < NN; i += gsize) { prm.flagL[i] = -1; prm.flagH[i] = -1; }

    {   // x copy (float4)
        const float4* src = (const float4*)prm.x_in;
        float4* dst = (float4*)prm.x;
        for (int i = gtid; i < NN * HH / 4; i += gsize) dst[i] = src[i];
    }
    {   // bucket: each block owns a contiguous chunk of NN/GBLK = 512 nodes
        if (tid < 36) lcnt[tid] = 0;
        __syncthreads();
        int base = bid * (NN / GBLK);
        int bkt[2], rnk[2];
        #pragma unroll
        for (int u = 0; u < 2; ++u) {
            int i = base + u * NTHR + tid;
            int d = prm.depths[i], s = prm.states[i];
            bkt[u] = -1; rnk[u] = 0;
            if (d >= 1 && (s == 0 || s == 1 || s == 3)) {
                int cat = (s == 3) ? 2 : s;
                bkt[u] = (d - 1) * 3 + cat;
                rnk[u] = atomicAdd(&lcnt[bkt[u]], 1);
            }
        }
        __syncthreads();
        if (tid < 36 && lcnt[tid] > 0) lbase[tid] = atomicAdd(&prm.cntB[tid], lcnt[tid]);
        __syncthreads();
        #pragma unroll
        for (int u = 0; u < 2; ++u) {
            if (bkt[u] >= 0) {
                int idx = lbase[bkt[u]] + rnk[u];
                if (idx < CAP) {
                    int dd = bkt[u] / 3, cat = bkt[u] - dd * 3;
                    int i = base + u * NTHR + tid;
                    int* lst = (cat == 0) ? prm.listL : (cat == 1) ? prm.listR : prm.listHd;
                    lst[dd * CAP + idx] = i;
                }
            }
        }
    }
    gbar(prm.bars, ++rnd);

    // ---------------- depth loop ------------------------------------------
    for (int d = MAXD; d >= 1; --d) {
        const int bi = d - 1;
        const int* listL  = prm.listL  + (size_t)bi * CAP;
        const int* listR  = prm.listR  + (size_t)bi * CAP;
        const int* listHd = prm.listHd + (size_t)bi * CAP;

        // ---- phase 1: mark parents, alloc slots, zero compact rows -------
        {
            int nL = min(prm.cntB[bi * 3 + 0], CAP);
            int nH = min(prm.cntB[bi * 3 + 2], CAP);
            if (tid < 2) lc[tid] = 0;
            __syncthreads();
            int t = gtid;   // gsize = 131072 >= nL+nH (<= 16384) always
            int p = -1, which = 0, rank = 0;
            if (t < nL + nH) {
                which = (t >= nL) ? 1 : 0;
                p = which ? prm.parents[listHd[t - nL]] : prm.parents[listL[t]];
                int* flag = which ? prm.flagH : prm.flagL;
                int old = atomicExch(&flag[p], d);
                if (old != d) rank = atomicAdd(&lc[which], 1);
                else p = -1;
            }
            __syncthreads();
            if (tid < 2 && lc[tid] > 0)
                lb[tid] = atomicAdd(&prm.cntA[(tid ? 12 : 0) + bi], lc[tid]);
            __syncthreads();
            if (p >= 0) {
                int s = lb[which] + rank;
                float4 z = make_float4(0.f, 0.f, 0.f, 0.f);
                if (which) {
                    prm.slotH[p] = s; prm.activeH[s] = p;
                    float4* a = (float4*)(prm.mh_c + (size_t)s * HH);
                    #pragma unroll
                    for (int q = 0; q < HH / 4; ++q) a[q] = z;
                } else {
                    prm.slotL[p] = s; prm.activeL[s] = p;
                    float4* a  = (float4*)(prm.left_c  + (size_t)s * HH);
                    float4* b2 = (float4*)(prm.right_c + (size_t)s * HH);
                    #pragma unroll
                    for (int q = 0; q < HH / 4; ++q) { a[q] = z; b2[q] = z; }
                }
            }
        }
        gbar(prm.bars, ++rnd);

        // ---- phase 2: lep MLP [0,G_LEP) || left/right scatter [G_LEP,GBLK)
        if (bid < G_LEP) {
            int nH = min(prm.cntB[bi * 3 + 2], CAP);
            for (int rb = bid; rb * 8 < nH; rb += G_LEP)
                mlp_core<1, HH + EE>(rb * 8, nH, tid, listHd, prm.parents, prm.slotH,
                                     prm.flagL, d, prm.x, prm.plef, nullptr,
                                     prm.pW1, prm.pb1, prm.pW2, prm.pb2,
                                     prm.mh_c, sh_raw);
        } else {
            int nL = min(prm.cntB[bi * 3 + 0], CAP);
            int nR = min(prm.cntB[bi * 3 + 1], CAP);
            int total = (nL + nR) * (HH / 4);
            for (int t = (bid - G_LEP) * NTHR + tid; t < total;
                 t += (GBLK - G_LEP) * NTHR) {
                int e = t >> 5, q = t & 31;
                int child;
                float* dst;
                if (e < nL) {
                    child = listL[e];
                    dst = prm.left_c + (size_t)prm.slotL[prm.parents[child]] * HH;
                } else {
                    child = listR[e - nL];
                    int p = prm.parents[child];
                    if (prm.flagL[p] != d) continue;   // no left sibling: never applied
                    dst = prm.right_c + (size_t)prm.slotL[p] * HH;
                }
                float4 v = ((const float4*)(prm.x + (size_t)child * HH))[q];
                atomicAdd(dst + q * 4 + 0, v.x);
                atomicAdd(dst + q * 4 + 1, v.y);
                atomicAdd(dst + q * 4 + 2, v.z);
                atomicAdd(dst + q * 4 + 3, v.w);
            }
        }
        gbar(prm.bars, ++rnd);

        // ---- phase 3: merger [0,G_MRG) || lem [G_MRG,GBLK) ---------------
        // merger writes x[p] for left-parents; lem reads x[p] for head-parents.
        // Overlap rows are exactly those where lem output is discarded (flagL
        // priority), so the read-write overlap there is harmless.
        if (bid < G_MRG) {
            int nA = min(prm.cntA[bi], CAP);
            for (int rb = bid; rb * 8 < nA; rb += G_MRG)
                mlp_core<0, 2 * HH + EE>(rb * 8, nA, tid, prm.activeL, prm.parents,
                                         nullptr, prm.flagL, d,
                                         prm.left_c, prm.right_c, prm.pef,
                                         prm.mW1, prm.mb1, prm.mW2, prm.mb2,
                                         prm.x, sh_raw);
        } else {
            int nB = min(prm.cntA[12 + bi], CAP);
            for (int rb = bid - G_MRG; rb * 8 < nB; rb += GBLK - G_MRG)
                mlp_core<2, 2 * HH>(rb * 8, nB, tid, prm.activeH, prm.parents,
                                    nullptr, prm.flagL, d,
                                    prm.x, prm.mh_c, nullptr,
                                    prm.eW1, prm.eb1, prm.eW2, prm.eb2,
                                    prm.x, sh_raw);
        }
        gbar(prm.bars, ++rnd);
    }
}

// ---------------------------------------------------------------------------
extern "C" void kernel_launch(void* const* d_in, const int* in_sizes, int n_in,
                              void* d_out, int out_size, void* d_ws, size_t ws_size,
                              hipStream_t stream) {
    CoopParams prm;
    prm.x_in    = (const float*)d_in[0];
    const int* edge = (const int*)d_in[1];
    prm.depths  = (const int*)d_in[2];
    prm.states  = (const int*)d_in[3];
    prm.pef     = (const float*)d_in[4];
    prm.plef    = (const float*)d_in[5];
    prm.mW1 = (const float*)d_in[6];  prm.mb1 = (const float*)d_in[7];
    prm.mW2 = (const float*)d_in[8];  prm.mb2 = (const float*)d_in[9];
    prm.pW1 = (const float*)d_in[10]; prm.pb1 = (const float*)d_in[11];
    prm.pW2 = (const float*)d_in[12]; prm.pb2 = (const float*)d_in[13];
    prm.eW1 = (const float*)d_in[14]; prm.eb1 = (const float*)d_in[15];
    prm.eW2 = (const float*)d_in[16]; prm.eb2 = (const float*)d_in[17];

    prm.x = (float*)d_out;
    prm.parents = edge + NN;

    char* w = (char*)d_ws;
    auto alloc = [&](size_t bytes) {
        void* p = (void*)w;
        w += (bytes + 255) & ~(size_t)255;
        return p;
    };
    // [0..35]=cntB, [36..59]=cntA, [64..319]=barrier (groups @64..+g*32, master @320)
    int* cnt_all = (int*)alloc(512 * 4);
    prm.cntB   = cnt_all;
    prm.cntA   = cnt_all + 36;
    prm.bars   = cnt_all + 64;
    prm.flagL  = (int*)alloc((size_t)NN * 4);
    prm.flagH  = (int*)alloc((size_t)NN * 4);
    prm.slotL  = (int*)alloc((size_t)NN * 4);
    prm.slotH  = (int*)alloc((size_t)NN * 4);
    prm.listL  = (int*)alloc((size_t)12 * CAP * 4);
    prm.listR  = (int*)alloc((size_t)12 * CAP * 4);
    prm.listHd = (int*)alloc((size_t)12 * CAP * 4);
    prm.activeL = (int*)alloc((size_t)CAP * 4);
    prm.activeH = (int*)alloc((size_t)CAP * 4);
    prm.left_c  = (float*)alloc((size_t)CAP * HH * 4);
    prm.right_c = (float*)alloc((size_t)CAP * HH * 4);
    prm.mh_c    = (float*)alloc((size_t)CAP * HH * 4);

    hipMemsetAsync(cnt_all, 0, 512 * 4, stream);   // zeroes cntB, cntA, barrier

    persist_kernel<<<dim3(GBLK), dim3(NTHR), 0, stream>>>(prm);
}